// Round 2
// baseline (4236.010 us; speedup 1.0000x reference)
//
#include <hip/hip_runtime.h>

typedef __attribute__((ext_vector_type(8))) short short8;
typedef __attribute__((ext_vector_type(4))) float f32x4;
typedef __attribute__((ext_vector_type(4))) int int4v;

__device__ __forceinline__ float bf2f(unsigned short u) {
  return __uint_as_float(((unsigned)u) << 16);
}
__device__ __forceinline__ unsigned short f2bf(float f) {
  unsigned u = __float_as_uint(f);
  return (unsigned short)((u + 0x7FFFu + ((u >> 16) & 1u)) >> 16);
}

// ---------------- CSR build ----------------
__global__ void count_kernel(const int* __restrict__ dst, int* __restrict__ cnt, int E) {
  int e = blockIdx.x * blockDim.x + threadIdx.x;
  if (e < E) atomicAdd(&cnt[dst[e] + 1], 1);
}

// single block, 1024 threads: inclusive scan of cnt[0..n) -> rowptr; cur[j]=row start
__global__ __launch_bounds__(1024) void scan_kernel(const int* __restrict__ cnt,
                                                    int* __restrict__ rowptr,
                                                    int* __restrict__ cur,
                                                    int n, int nrows) {
  __shared__ int buf[2][1024];
  int tid = threadIdx.x;
  int C = (n + 1023) >> 10;
  int start = tid * C;
  int end = start + C; if (end > n) end = n;
  int s = 0;
  for (int j = start; j < end; j++) s += cnt[j];
  buf[0][tid] = s;
  __syncthreads();
  int pin = 0;
  for (int off = 1; off < 1024; off <<= 1) {
    int v = buf[pin][tid];
    if (tid >= off) v += buf[pin][tid - off];
    buf[pin ^ 1][tid] = v;
    pin ^= 1;
    __syncthreads();
  }
  int base = (tid == 0) ? 0 : buf[pin][tid - 1];
  for (int j = start; j < end; j++) {
    base += cnt[j];
    rowptr[j] = base;  // inclusive scan of cnt == exclusive prefix of degrees == row start
  }
  for (int j = start; j < end; j++) {
    if (j < nrows) cur[j] = rowptr[j];
  }
}

__global__ void fill_kernel(const int* __restrict__ src, const int* __restrict__ dst,
                            const float* __restrict__ ew,
                            int* __restrict__ cur, int* __restrict__ s_src,
                            float* __restrict__ s_ew, int E) {
  int e = blockIdx.x * blockDim.x + threadIdx.x;
  if (e >= E) return;
  int r = dst[e];
  int pos = atomicAdd(&cur[r], 1);
  s_src[pos] = src[e];
  s_ew[pos] = ew[e];
}

// ---------------- weight prep: f32 -> bf16, transpose to [col][k] ----------------
// Wt1: [384][960]  (cols 0..191 from w1, 192..383 from l1); Wtb: [12][384][192]
__global__ void prep_w_kernel(const float* __restrict__ w1,
                              const float* __restrict__ l1,
                              const float* __restrict__ wb,
                              const float* __restrict__ lb,
                              unsigned short* __restrict__ Wt1,
                              unsigned short* __restrict__ Wtb) {
  int tid = blockIdx.x * blockDim.x + threadIdx.x;
  const int n1 = 384 * 960;
  const int nb = 12 * 384 * 192;
  if (tid < n1) {
    int c = tid / 960, k = tid % 960;
    Wt1[tid] = f2bf((c < 192) ? w1[k * 192 + c] : l1[k * 192 + (c - 192)]);
  } else if (tid < n1 + nb) {
    int u = tid - n1;
    int i = u / (384 * 192);
    int r = u % (384 * 192);
    int c = r / 192, k = r % 192;
    Wtb[u] = f2bf((c < 192) ? wb[(i * 192 + k) * 192 + c]
                            : lb[(i * 192 + k) * 192 + (c - 192)]);
  }
}

// ---------------- GEMM: t[N][384] = A[N][K] @ Wt^T  (Wt is [384][K] bf16) ----------------
__device__ __forceinline__ short8 load_afrag(const unsigned short* p) {
  return *reinterpret_cast<const short8*>(p);
}
__device__ __forceinline__ short8 load_afrag(const float* p) {
  f32x4 a = *reinterpret_cast<const f32x4*>(p);
  f32x4 b = *reinterpret_cast<const f32x4*>(p + 4);
  short8 r;
  r[0] = (short)f2bf(a[0]); r[1] = (short)f2bf(a[1]);
  r[2] = (short)f2bf(a[2]); r[3] = (short)f2bf(a[3]);
  r[4] = (short)f2bf(b[0]); r[5] = (short)f2bf(b[1]);
  r[6] = (short)f2bf(b[2]); r[7] = (short)f2bf(b[3]);
  return r;
}

// 8 waves/block; wave w: rows blockIdx*64 + (w>>1)*16, col half (w&1)*192 (12 frags)
template <typename T>
__global__ __launch_bounds__(512) void gemm_kernel(const T* __restrict__ A,
                                                   const unsigned short* __restrict__ Wt,
                                                   unsigned short* __restrict__ out,
                                                   int nrows, int K) {
  int w = threadIdx.x >> 6;
  int lane = threadIdx.x & 63;
  int row0 = blockIdx.x * 64 + (w >> 1) * 16;
  int arow = row0 + (lane & 15);
  if (arow > nrows - 1) arow = nrows - 1;
  int chalf = (w & 1) * 192;
  int kq = (lane >> 4) * 8;
  int lcol = lane & 15;

  f32x4 acc[12];
#pragma unroll
  for (int i = 0; i < 12; i++) acc[i] = (f32x4)(0.0f);

  const T* Ap = A + (size_t)arow * K + kq;
  const unsigned short* Bp = Wt + (size_t)(chalf + lcol) * K + kq;

  for (int k0 = 0; k0 < K; k0 += 32) {
    short8 afrag = load_afrag(Ap + k0);
#pragma unroll
    for (int cf = 0; cf < 12; cf++) {
      short8 bfrag = *reinterpret_cast<const short8*>(Bp + (size_t)cf * 16 * K + k0);
      acc[cf] = __builtin_amdgcn_mfma_f32_16x16x32_bf16(afrag, bfrag, acc[cf], 0, 0, 0);
    }
  }

  int rbase = row0 + (lane >> 4) * 4;
#pragma unroll
  for (int cf = 0; cf < 12; cf++) {
    int col = chalf + cf * 16 + lcol;
#pragma unroll
    for (int r = 0; r < 4; r++) {
      int row = rbase + r;
      if (row < nrows) out[(size_t)row * 384 + col] = f2bf(acc[cf][r]);
    }
  }
}

// ---------------- SpMM + epilogue ----------------
// t: [N][384] bf16, cols 0..191 = h@w ; cols 192..383 = h@lw
// thread = (node, chunk c of 8 cols)
// mode 0: r = agg + hl + bias           -> out16 (+out32 if given)
// mode 1: r = 0.5*(hprev32 + agg + hl + bias) -> out16 + out32
__global__ __launch_bounds__(256) void spmm_kernel(const unsigned short* __restrict__ t,
                                                   const int* __restrict__ rowptr,
                                                   const int* __restrict__ s_src,
                                                   const float* __restrict__ s_ew,
                                                   const float* __restrict__ bias,
                                                   const float* __restrict__ hprev32,
                                                   unsigned short* __restrict__ out16,
                                                   float* __restrict__ out32,
                                                   int n, int mode) {
  int tid = blockIdx.x * blockDim.x + threadIdx.x;
  int node = tid / 24;
  int c = tid % 24;
  if (node >= n) return;

  float acc[8];
#pragma unroll
  for (int j = 0; j < 8; j++) acc[j] = 0.0f;

  int e0 = rowptr[node], e1 = rowptr[node + 1];
  for (int e = e0; e < e1; e++) {
    int s = s_src[e];
    float wgt = s_ew[e];
    short8 v = *reinterpret_cast<const short8*>(&t[(size_t)s * 384 + c * 8]);
#pragma unroll
    for (int j = 0; j < 8; j++) acc[j] += wgt * bf2f((unsigned short)v[j]);
  }

  short8 hlv = *reinterpret_cast<const short8*>(&t[(size_t)node * 384 + 192 + c * 8]);
  float r[8];
#pragma unroll
  for (int j = 0; j < 8; j++)
    r[j] = acc[j] + bf2f((unsigned short)hlv[j]) + bias[c * 8 + j];

  if (mode == 1) {
#pragma unroll
    for (int j = 0; j < 8; j++)
      r[j] = 0.5f * (hprev32[(size_t)node * 192 + c * 8 + j] + r[j]);
  }

  unsigned short o16[8];
#pragma unroll
  for (int j = 0; j < 8; j++) o16[j] = f2bf(r[j]);
  *reinterpret_cast<int4v*>(&out16[(size_t)node * 192 + c * 8]) =
      *reinterpret_cast<const int4v*>(o16);

  if (out32) {
    f32x4 lo, hi;
    lo[0] = r[0]; lo[1] = r[1]; lo[2] = r[2]; lo[3] = r[3];
    hi[0] = r[4]; hi[1] = r[5]; hi[2] = r[6]; hi[3] = r[7];
    *reinterpret_cast<f32x4*>(&out32[(size_t)node * 192 + c * 8]) = lo;
    *reinterpret_cast<f32x4*>(&out32[(size_t)node * 192 + c * 8 + 4]) = hi;
  }
}

// ---------------- conv2 (f32) ----------------
__global__ __launch_bounds__(256) void conv2a_kernel(const float* __restrict__ h,
                                                     const float* __restrict__ w2,
                                                     const float* __restrict__ l2,
                                                     const float* __restrict__ b2,
                                                     float* __restrict__ sup2,
                                                     float* __restrict__ hl2, int n) {
  int wid = (blockIdx.x * blockDim.x + threadIdx.x) >> 6;
  int lane = threadIdx.x & 63;
  if (wid >= n) return;
  float sa[3] = {0.f, 0.f, 0.f}, sl[3] = {0.f, 0.f, 0.f};
  for (int k = lane; k < 192; k += 64) {
    float hv = h[(size_t)wid * 192 + k];
#pragma unroll
    for (int j = 0; j < 3; j++) {
      sa[j] += hv * w2[k * 3 + j];
      sl[j] += hv * l2[k * 3 + j];
    }
  }
#pragma unroll
  for (int j = 0; j < 3; j++) {
    for (int off = 32; off > 0; off >>= 1) {
      sa[j] += __shfl_down(sa[j], off);
      sl[j] += __shfl_down(sl[j], off);
    }
  }
  if (lane == 0) {
#pragma unroll
    for (int j = 0; j < 3; j++) {
      sup2[(size_t)wid * 3 + j] = sa[j];
      hl2[(size_t)wid * 3 + j] = sl[j] + b2[j];
    }
  }
}

__global__ __launch_bounds__(256) void conv2b_kernel(const int* __restrict__ rowptr,
                                                     const int* __restrict__ s_src,
                                                     const float* __restrict__ s_ew,
                                                     const float* __restrict__ sup2,
                                                     const float* __restrict__ hl2,
                                                     float* __restrict__ out, int n) {
  int node = blockIdx.x * blockDim.x + threadIdx.x;
  if (node >= n) return;
  float acc[3] = {0.f, 0.f, 0.f};
  int e0 = rowptr[node], e1 = rowptr[node + 1];
  for (int e = e0; e < e1; e++) {
    int s = s_src[e];
    float wgt = s_ew[e];
#pragma unroll
    for (int j = 0; j < 3; j++) acc[j] += wgt * sup2[(size_t)s * 3 + j];
  }
#pragma unroll
  for (int j = 0; j < 3; j++)
    out[(size_t)node * 3 + j] = acc[j] + hl2[(size_t)node * 3 + j];
}

extern "C" void kernel_launch(void* const* d_in, const int* in_sizes, int n_in,
                              void* d_out, int out_size, void* d_ws, size_t ws_size,
                              hipStream_t stream) {
  const float* x  = (const float*)d_in[0];
  const int* src  = (const int*)d_in[1];
  const int* dst  = (const int*)d_in[2];
  const float* ew = (const float*)d_in[3];
  const float* w1 = (const float*)d_in[4];
  const float* l1 = (const float*)d_in[5];
  const float* b1 = (const float*)d_in[6];
  const float* wb = (const float*)d_in[7];
  const float* lb = (const float*)d_in[8];
  const float* bb = (const float*)d_in[9];
  const float* w2 = (const float*)d_in[10];
  const float* l2 = (const float*)d_in[11];
  const float* b2 = (const float*)d_in[12];
  float* out = (float*)d_out;

  const int N = in_sizes[0] / 960;   // 100000
  const int E = in_sizes[1];         // 1600000

  float* h32 = out + (size_t)N * 3;  // x_cat region doubles as the f32 master h

  char* p = (char*)d_ws;
  auto alloc = [&](size_t bytes) {
    char* q = p;
    p += (bytes + 255) & ~(size_t)255;
    return q;
  };
  unsigned short* Wt1 = (unsigned short*)alloc((size_t)384 * 960 * 2);
  unsigned short* Wtb = (unsigned short*)alloc((size_t)12 * 384 * 192 * 2);
  unsigned short* t   = (unsigned short*)alloc((size_t)N * 384 * 2);
  unsigned short* h16 = (unsigned short*)alloc((size_t)N * 192 * 2);
  unsigned short* a16 = (unsigned short*)alloc((size_t)N * 192 * 2);
  int* rowptr = (int*)alloc((size_t)(N + 1) * 4);
  int* cur    = (int*)alloc((size_t)N * 4);
  int* cnt    = (int*)alloc((size_t)(N + 1) * 4);
  int* s_src  = (int*)alloc((size_t)E * 4);
  float* s_ew = (float*)alloc((size_t)E * 4);
  float* sup2 = (float*)alloc((size_t)N * 3 * 4);
  float* hl2  = (float*)alloc((size_t)N * 3 * 4);
  if ((size_t)(p - (char*)d_ws) > ws_size) return;  // signature: absmax stays 0.157

  hipMemsetAsync(cnt, 0, (size_t)(N + 1) * 4, stream);
  count_kernel<<<(E + 255) / 256, 256, 0, stream>>>(dst, cnt, E);
  scan_kernel<<<1, 1024, 0, stream>>>(cnt, rowptr, cur, N + 1, N);
  fill_kernel<<<(E + 255) / 256, 256, 0, stream>>>(src, dst, ew, cur, s_src, s_ew, E);
  {
    int total = 384 * 960 + 12 * 384 * 192;
    prep_w_kernel<<<(total + 255) / 256, 256, 0, stream>>>(w1, l1, wb, lb, Wt1, Wtb);
  }

  int gBlocks = (N + 63) / 64;
  int sBlocks = (N * 24 + 255) / 256;

  // conv1: t = [x@w1 | x@l1]; h = agg + hl + b1  (write f32 master + bf16 mirror)
  gemm_kernel<float><<<gBlocks, 512, 0, stream>>>(x, Wt1, t, N, 960);
  spmm_kernel<<<sBlocks, 256, 0, stream>>>(t, rowptr, s_src, s_ew, b1,
                                           (const float*)nullptr, h16, h32, N, 0);

  // res blocks
  for (int i = 0; i < 12; i += 2) {
    gemm_kernel<unsigned short><<<gBlocks, 512, 0, stream>>>(
        h16, Wtb + (size_t)i * 384 * 192, t, N, 192);
    spmm_kernel<<<sBlocks, 256, 0, stream>>>(t, rowptr, s_src, s_ew, bb + (size_t)i * 192,
                                             (const float*)nullptr, a16, (float*)nullptr, N, 0);
    gemm_kernel<unsigned short><<<gBlocks, 512, 0, stream>>>(
        a16, Wtb + (size_t)(i + 1) * 384 * 192, t, N, 192);
    spmm_kernel<<<sBlocks, 256, 0, stream>>>(t, rowptr, s_src, s_ew, bb + (size_t)(i + 1) * 192,
                                             h32, h16, h32, N, 1);
  }

  // conv2 (f32): x_out = agg(h@w2) + h@l2 + b2
  conv2a_kernel<<<(N + 3) / 4, 256, 0, stream>>>(h32, w2, l2, b2, sup2, hl2, N);
  conv2b_kernel<<<(N + 255) / 256, 256, 0, stream>>>(rowptr, s_src, s_ew, sup2, hl2, out, N);
  // x_cat == h32 already lives in the output buffer
}

// Round 3
// 3478.402 us; speedup vs baseline: 1.2178x; 1.2178x over previous
//
#include <hip/hip_runtime.h>

typedef __attribute__((ext_vector_type(8))) short short8;
typedef __attribute__((ext_vector_type(4))) float f32x4;
typedef __attribute__((ext_vector_type(4))) int int4v;
typedef __attribute__((ext_vector_type(2))) unsigned int u32x2;

__device__ __forceinline__ float bf2f(unsigned short u) {
  return __uint_as_float(((unsigned)u) << 16);
}
__device__ __forceinline__ unsigned short f2bf(float f) {
  unsigned u = __float_as_uint(f);
  return (unsigned short)((u + 0x7FFFu + ((u >> 16) & 1u)) >> 16);
}

#define GLB_CAST(p) ((const __attribute__((address_space(1))) void*)(p))
#define LDS_CAST(p) ((__attribute__((address_space(3))) void*)(p))

// ---------------- CSR build ----------------
__global__ void count_kernel(const int* __restrict__ dst, int* __restrict__ cnt, int E) {
  int e = blockIdx.x * blockDim.x + threadIdx.x;
  if (e < E) atomicAdd(&cnt[dst[e] + 1], 1);
}

__global__ __launch_bounds__(1024) void scan_kernel(const int* __restrict__ cnt,
                                                    int* __restrict__ rowptr,
                                                    int* __restrict__ cur,
                                                    int n, int nrows) {
  __shared__ int buf[2][1024];
  int tid = threadIdx.x;
  int C = (n + 1023) >> 10;
  int start = tid * C;
  int end = start + C; if (end > n) end = n;
  int s = 0;
  for (int j = start; j < end; j++) s += cnt[j];
  buf[0][tid] = s;
  __syncthreads();
  int pin = 0;
  for (int off = 1; off < 1024; off <<= 1) {
    int v = buf[pin][tid];
    if (tid >= off) v += buf[pin][tid - off];
    buf[pin ^ 1][tid] = v;
    pin ^= 1;
    __syncthreads();
  }
  int base = (tid == 0) ? 0 : buf[pin][tid - 1];
  for (int j = start; j < end; j++) {
    base += cnt[j];
    rowptr[j] = base;  // inclusive scan of cnt == row start for row j
  }
  for (int j = start; j < end; j++) {
    if (j < nrows) cur[j] = rowptr[j];
  }
}

__global__ void fill_kernel(const int* __restrict__ src, const int* __restrict__ dst,
                            const float* __restrict__ ew,
                            int* __restrict__ cur, int2* __restrict__ s_edge, int E) {
  int e = blockIdx.x * blockDim.x + threadIdx.x;
  if (e >= E) return;
  int r = dst[e];
  int pos = atomicAdd(&cur[r], 1);
  s_edge[pos] = make_int2(src[e], __float_as_int(ew[e]));
}

// ---------------- weight prep: f32 -> bf16, transpose to [col][k] ----------------
__global__ void prep_w_kernel(const float* __restrict__ w1,
                              const float* __restrict__ l1,
                              const float* __restrict__ wb,
                              const float* __restrict__ lb,
                              unsigned short* __restrict__ Wt1,
                              unsigned short* __restrict__ Wtb) {
  int tid = blockIdx.x * blockDim.x + threadIdx.x;
  const int n1 = 384 * 960;
  const int nb = 12 * 384 * 192;
  if (tid < n1) {
    int c = tid / 960, k = tid % 960;
    Wt1[tid] = f2bf((c < 192) ? w1[k * 192 + c] : l1[k * 192 + (c - 192)]);
  } else if (tid < n1 + nb) {
    int u = tid - n1;
    int i = u / (384 * 192);
    int r = u % (384 * 192);
    int c = r / 192, k = r % 192;
    Wtb[u] = f2bf((c < 192) ? wb[(i * 192 + k) * 192 + c]
                            : lb[(i * 192 + k) * 192 + (c - 192)]);
  }
}

// ---------------- GEMM: t[N][384] = A[N][K] @ Wt^T  (Wt [384][K] bf16) ----------------
__device__ __forceinline__ short8 load_afrag(const unsigned short* p) {
  return *reinterpret_cast<const short8*>(p);
}
__device__ __forceinline__ short8 load_afrag(const float* p) {
  f32x4 a = *reinterpret_cast<const f32x4*>(p);
  f32x4 b = *reinterpret_cast<const f32x4*>(p + 4);
  short8 r;
  r[0] = (short)f2bf(a[0]); r[1] = (short)f2bf(a[1]);
  r[2] = (short)f2bf(a[2]); r[3] = (short)f2bf(a[3]);
  r[4] = (short)f2bf(b[0]); r[5] = (short)f2bf(b[1]);
  r[6] = (short)f2bf(b[2]); r[7] = (short)f2bf(b[3]);
  return r;
}

// block: 512 thr (8 waves), 256 rows x 384 cols. wave: rg=w>>1 (64 rows), ch=w&1 (192 cols).
// LDS B-tile per K-tile of 96: layout slot=(kq*384+c), 16B each -> 73728 B, conflict-free b128.
// K must be a multiple of 96 (960 and 192 both are).
template <typename T>
__global__ __launch_bounds__(512) void gemm_kernel(const T* __restrict__ A,
                                                   const unsigned short* __restrict__ Wt,
                                                   unsigned short* __restrict__ out,
                                                   int nrows, int K) {
  extern __shared__ char lds_raw[];

  int tid = threadIdx.x;
  int lane = tid & 63;
  int w = tid >> 6;
  int rg = w >> 1, ch = w & 1;
  int row0 = blockIdx.x * 256 + rg * 64;
  int l15 = lane & 15, lq = lane >> 4;

  f32x4 acc[12][4];
#pragma unroll
  for (int cf = 0; cf < 12; cf++)
#pragma unroll
    for (int rf = 0; rf < 4; rf++) acc[cf][rf] = (f32x4)(0.0f);

  const T* ap[4];
#pragma unroll
  for (int rf = 0; rf < 4; rf++) {
    int r = row0 + rf * 16 + l15;
    if (r > nrows - 1) r = nrows - 1;
    ap[rf] = A + (size_t)r * K + lq * 8;
  }

  int tiles = K / 96;
  for (int tile = 0; tile < tiles; ++tile) {
    __syncthreads();
    // stage B-tile: 4608 slots of 16B; slot = kq*384 + c ; src = Wt[c][tile*96 + kq*8 ..+8]
#pragma unroll
    for (int it = 0; it < 9; ++it) {
      int slot = it * 512 + tid;
      int q = slot / 384, c = slot % 384;
      const unsigned short* g = Wt + (size_t)c * K + tile * 96 + q * 8;
      __builtin_amdgcn_global_load_lds(GLB_CAST(g), LDS_CAST(lds_raw + slot * 16), 16, 0, 0);
    }
    __syncthreads();

#pragma unroll
    for (int ks = 0; ks < 3; ++ks) {
      int k0 = tile * 96 + ks * 32;
      short8 af[4];
#pragma unroll
      for (int rf = 0; rf < 4; rf++) af[rf] = load_afrag(ap[rf] + k0);
#pragma unroll
      for (int cf = 0; cf < 12; cf++) {
        const short8 bf = *reinterpret_cast<const short8*>(
            lds_raw + (((ks * 4 + lq) * 384) + ch * 192 + cf * 16 + l15) * 16);
#pragma unroll
        for (int rf = 0; rf < 4; rf++)
          acc[cf][rf] = __builtin_amdgcn_mfma_f32_16x16x32_bf16(bf, af[rf], acc[cf][rf], 0, 0, 0);
      }
    }
  }

  // epilogue: lane holds rows row0+rf*16+l15, cols ch*192+cf*16+lq*4 .. +4
#pragma unroll
  for (int rf = 0; rf < 4; rf++) {
    int row = row0 + rf * 16 + l15;
    if (row >= nrows) continue;
    unsigned short* orow = out + (size_t)row * 384 + ch * 192 + lq * 4;
#pragma unroll
    for (int cf = 0; cf < 12; cf++) {
      u32x2 pv;
      pv[0] = (unsigned)f2bf(acc[cf][rf][0]) | ((unsigned)f2bf(acc[cf][rf][1]) << 16);
      pv[1] = (unsigned)f2bf(acc[cf][rf][2]) | ((unsigned)f2bf(acc[cf][rf][3]) << 16);
      *reinterpret_cast<u32x2*>(orow + cf * 16) = pv;
    }
  }
}

// ---------------- SpMM + epilogue ----------------
// t: [N][384] bf16, cols 0..191 = h@w ; cols 192..383 = h@lw
// thread = (node, chunk c of 8 cols)
// mode 0: r = agg + hl + bias            -> out16 (+out32 if given)
// mode 1: r = 0.5*(hprev32 + agg + hl + bias) -> out16 + out32
__global__ __launch_bounds__(256) void spmm_kernel(const unsigned short* __restrict__ t,
                                                   const int* __restrict__ rowptr,
                                                   const int2* __restrict__ s_edge,
                                                   const float* __restrict__ bias,
                                                   const float* __restrict__ hprev32,
                                                   unsigned short* __restrict__ out16,
                                                   float* __restrict__ out32,
                                                   int n, int mode) {
  int tid = blockIdx.x * blockDim.x + threadIdx.x;
  int node = tid / 24;
  int c = tid % 24;
  if (node >= n) return;

  float acc[8];
#pragma unroll
  for (int j = 0; j < 8; j++) acc[j] = 0.0f;

  int e0 = rowptr[node], e1 = rowptr[node + 1];
  for (int e = e0; e < e1; e++) {
    int2 rec = s_edge[e];
    float wgt = __int_as_float(rec.y);
    short8 v = *reinterpret_cast<const short8*>(&t[(size_t)rec.x * 384 + c * 8]);
#pragma unroll
    for (int j = 0; j < 8; j++) acc[j] += wgt * bf2f((unsigned short)v[j]);
  }

  short8 hlv = *reinterpret_cast<const short8*>(&t[(size_t)node * 384 + 192 + c * 8]);
  float r[8];
#pragma unroll
  for (int j = 0; j < 8; j++)
    r[j] = acc[j] + bf2f((unsigned short)hlv[j]) + bias[c * 8 + j];

  if (mode == 1) {
#pragma unroll
    for (int j = 0; j < 8; j++)
      r[j] = 0.5f * (hprev32[(size_t)node * 192 + c * 8 + j] + r[j]);
  }

  unsigned short o16[8];
#pragma unroll
  for (int j = 0; j < 8; j++) o16[j] = f2bf(r[j]);
  *reinterpret_cast<int4v*>(&out16[(size_t)node * 192 + c * 8]) =
      *reinterpret_cast<const int4v*>(o16);

  if (out32) {
    f32x4 lo, hi;
    lo[0] = r[0]; lo[1] = r[1]; lo[2] = r[2]; lo[3] = r[3];
    hi[0] = r[4]; hi[1] = r[5]; hi[2] = r[6]; hi[3] = r[7];
    *reinterpret_cast<f32x4*>(&out32[(size_t)node * 192 + c * 8]) = lo;
    *reinterpret_cast<f32x4*>(&out32[(size_t)node * 192 + c * 8 + 4]) = hi;
  }
}

// ---------------- conv2 (f32) ----------------
__global__ __launch_bounds__(256) void conv2a_kernel(const float* __restrict__ h,
                                                     const float* __restrict__ w2,
                                                     const float* __restrict__ l2,
                                                     const float* __restrict__ b2,
                                                     float* __restrict__ sup2,
                                                     float* __restrict__ hl2, int n) {
  int wid = (blockIdx.x * blockDim.x + threadIdx.x) >> 6;
  int lane = threadIdx.x & 63;
  if (wid >= n) return;
  float sa[3] = {0.f, 0.f, 0.f}, sl[3] = {0.f, 0.f, 0.f};
  for (int k = lane; k < 192; k += 64) {
    float hv = h[(size_t)wid * 192 + k];
#pragma unroll
    for (int j = 0; j < 3; j++) {
      sa[j] += hv * w2[k * 3 + j];
      sl[j] += hv * l2[k * 3 + j];
    }
  }
#pragma unroll
  for (int j = 0; j < 3; j++) {
    for (int off = 32; off > 0; off >>= 1) {
      sa[j] += __shfl_down(sa[j], off);
      sl[j] += __shfl_down(sl[j], off);
    }
  }
  if (lane == 0) {
#pragma unroll
    for (int j = 0; j < 3; j++) {
      sup2[(size_t)wid * 3 + j] = sa[j];
      hl2[(size_t)wid * 3 + j] = sl[j] + b2[j];
    }
  }
}

__global__ __launch_bounds__(256) void conv2b_kernel(const int* __restrict__ rowptr,
                                                     const int2* __restrict__ s_edge,
                                                     const float* __restrict__ sup2,
                                                     const float* __restrict__ hl2,
                                                     float* __restrict__ out, int n) {
  int node = blockIdx.x * blockDim.x + threadIdx.x;
  if (node >= n) return;
  float acc[3] = {0.f, 0.f, 0.f};
  int e0 = rowptr[node], e1 = rowptr[node + 1];
  for (int e = e0; e < e1; e++) {
    int2 rec = s_edge[e];
    float wgt = __int_as_float(rec.y);
#pragma unroll
    for (int j = 0; j < 3; j++) acc[j] += wgt * sup2[(size_t)rec.x * 3 + j];
  }
#pragma unroll
  for (int j = 0; j < 3; j++)
    out[(size_t)node * 3 + j] = acc[j] + hl2[(size_t)node * 3 + j];
}

extern "C" void kernel_launch(void* const* d_in, const int* in_sizes, int n_in,
                              void* d_out, int out_size, void* d_ws, size_t ws_size,
                              hipStream_t stream) {
  const float* x  = (const float*)d_in[0];
  const int* src  = (const int*)d_in[1];
  const int* dst  = (const int*)d_in[2];
  const float* ew = (const float*)d_in[3];
  const float* w1 = (const float*)d_in[4];
  const float* l1 = (const float*)d_in[5];
  const float* b1 = (const float*)d_in[6];
  const float* wb = (const float*)d_in[7];
  const float* lb = (const float*)d_in[8];
  const float* bb = (const float*)d_in[9];
  const float* w2 = (const float*)d_in[10];
  const float* l2 = (const float*)d_in[11];
  const float* b2 = (const float*)d_in[12];
  float* out = (float*)d_out;

  const int N = in_sizes[0] / 960;   // 100000
  const int E = in_sizes[1];         // 1600000

  float* h32 = out + (size_t)N * 3;  // x_cat region doubles as the f32 master h

  char* p = (char*)d_ws;
  auto alloc = [&](size_t bytes) {
    char* q = p;
    p += (bytes + 255) & ~(size_t)255;
    return q;
  };
  unsigned short* Wt1 = (unsigned short*)alloc((size_t)384 * 960 * 2);
  unsigned short* Wtb = (unsigned short*)alloc((size_t)12 * 384 * 192 * 2);
  unsigned short* t   = (unsigned short*)alloc((size_t)N * 384 * 2);
  unsigned short* h16 = (unsigned short*)alloc((size_t)N * 192 * 2);
  unsigned short* a16 = (unsigned short*)alloc((size_t)N * 192 * 2);
  int* rowptr = (int*)alloc((size_t)(N + 1) * 4);
  int* cur    = (int*)alloc((size_t)N * 4);
  int* cnt    = (int*)alloc((size_t)(N + 1) * 4);
  int2* s_edge = (int2*)alloc((size_t)E * 8);
  float* sup2 = (float*)alloc((size_t)N * 3 * 4);
  float* hl2  = (float*)alloc((size_t)N * 3 * 4);
  if ((size_t)(p - (char*)d_ws) > ws_size) return;  // signature: absmax stays 0.157

  hipMemsetAsync(cnt, 0, (size_t)(N + 1) * 4, stream);
  count_kernel<<<(E + 255) / 256, 256, 0, stream>>>(dst, cnt, E);
  scan_kernel<<<1, 1024, 0, stream>>>(cnt, rowptr, cur, N + 1, N);
  fill_kernel<<<(E + 255) / 256, 256, 0, stream>>>(src, dst, ew, cur, s_edge, E);
  {
    int total = 384 * 960 + 12 * 384 * 192;
    prep_w_kernel<<<(total + 255) / 256, 256, 0, stream>>>(w1, l1, wb, lb, Wt1, Wtb);
  }

  const int LDS_BYTES = 73728;
  int gBlocks = (N + 255) / 256;
  int sBlocks = (N * 24 + 255) / 256;

  // conv1: t = [x@w1 | x@l1]; h = agg + hl + b1  (f32 master + bf16 mirror)
  gemm_kernel<float><<<gBlocks, 512, LDS_BYTES, stream>>>(x, Wt1, t, N, 960);
  spmm_kernel<<<sBlocks, 256, 0, stream>>>(t, rowptr, s_edge, b1,
                                           (const float*)nullptr, h16, h32, N, 0);

  // res blocks
  for (int i = 0; i < 12; i += 2) {
    gemm_kernel<unsigned short><<<gBlocks, 512, LDS_BYTES, stream>>>(
        h16, Wtb + (size_t)i * 384 * 192, t, N, 192);
    spmm_kernel<<<sBlocks, 256, 0, stream>>>(t, rowptr, s_edge, bb + (size_t)i * 192,
                                             (const float*)nullptr, a16, (float*)nullptr, N, 0);
    gemm_kernel<unsigned short><<<gBlocks, 512, LDS_BYTES, stream>>>(
        a16, Wtb + (size_t)(i + 1) * 384 * 192, t, N, 192);
    spmm_kernel<<<sBlocks, 256, 0, stream>>>(t, rowptr, s_edge, bb + (size_t)(i + 1) * 192,
                                             h32, h16, h32, N, 1);
  }

  // conv2 (f32): x_out = agg(h@w2) + h@l2 + b2
  conv2a_kernel<<<(N + 3) / 4, 256, 0, stream>>>(h32, w2, l2, b2, sup2, hl2, N);
  conv2b_kernel<<<(N + 255) / 256, 256, 0, stream>>>(rowptr, s_edge, sup2, hl2, out, N);
  // x_cat == h32 already lives in the output buffer
}

// Round 4
// 2911.754 us; speedup vs baseline: 1.4548x; 1.1946x over previous
//
#include <hip/hip_runtime.h>

typedef __attribute__((ext_vector_type(8))) short short8;
typedef __attribute__((ext_vector_type(4))) float f32x4;
typedef __attribute__((ext_vector_type(4))) int int4v;
typedef __attribute__((ext_vector_type(2))) unsigned int u32x2;

__device__ __forceinline__ float bf2f(unsigned short u) {
  return __uint_as_float(((unsigned)u) << 16);
}
__device__ __forceinline__ unsigned short f2bf(float f) {
  unsigned u = __float_as_uint(f);
  return (unsigned short)((u + 0x7FFFu + ((u >> 16) & 1u)) >> 16);
}

#define GLB_CAST(p) ((const __attribute__((address_space(1))) void*)(p))
#define LDS_CAST(p) ((__attribute__((address_space(3))) void*)(p))

// ---------------- CSR build ----------------
__global__ void count_kernel(const int* __restrict__ dst, int* __restrict__ cnt, int E) {
  int e = blockIdx.x * blockDim.x + threadIdx.x;
  if (e < E) atomicAdd(&cnt[dst[e] + 1], 1);
}

__global__ __launch_bounds__(1024) void scan_kernel(const int* __restrict__ cnt,
                                                    int* __restrict__ rowptr,
                                                    int* __restrict__ cur,
                                                    int n, int nrows) {
  __shared__ int buf[2][1024];
  int tid = threadIdx.x;
  int C = (n + 1023) >> 10;
  int start = tid * C;
  int end = start + C; if (end > n) end = n;
  int s = 0;
  for (int j = start; j < end; j++) s += cnt[j];
  buf[0][tid] = s;
  __syncthreads();
  int pin = 0;
  for (int off = 1; off < 1024; off <<= 1) {
    int v = buf[pin][tid];
    if (tid >= off) v += buf[pin][tid - off];
    buf[pin ^ 1][tid] = v;
    pin ^= 1;
    __syncthreads();
  }
  int base = (tid == 0) ? 0 : buf[pin][tid - 1];
  for (int j = start; j < end; j++) {
    base += cnt[j];
    rowptr[j] = base;  // inclusive scan of cnt == row start for row j
  }
  for (int j = start; j < end; j++) {
    if (j < nrows) cur[j] = rowptr[j];
  }
}

__global__ void fill_kernel(const int* __restrict__ src, const int* __restrict__ dst,
                            const float* __restrict__ ew,
                            int* __restrict__ cur, int2* __restrict__ s_edge, int E) {
  int e = blockIdx.x * blockDim.x + threadIdx.x;
  if (e >= E) return;
  int r = dst[e];
  int pos = atomicAdd(&cur[r], 1);
  s_edge[pos] = make_int2(src[e], __float_as_int(ew[e]));
}

// ---------------- weight prep: f32 -> bf16, transpose to [col][k] ----------------
__global__ void prep_w_kernel(const float* __restrict__ w1,
                              const float* __restrict__ l1,
                              const float* __restrict__ wb,
                              const float* __restrict__ lb,
                              unsigned short* __restrict__ Wt1,
                              unsigned short* __restrict__ Wtb) {
  int tid = blockIdx.x * blockDim.x + threadIdx.x;
  const int n1 = 384 * 960;
  const int nb = 12 * 384 * 192;
  if (tid < n1) {
    int c = tid / 960, k = tid % 960;
    Wt1[tid] = f2bf((c < 192) ? w1[k * 192 + c] : l1[k * 192 + (c - 192)]);
  } else if (tid < n1 + nb) {
    int u = tid - n1;
    int i = u / (384 * 192);
    int r = u % (384 * 192);
    int c = r / 192, k = r % 192;
    Wtb[u] = f2bf((c < 192) ? wb[(i * 192 + k) * 192 + c]
                            : lb[(i * 192 + k) * 192 + (c - 192)]);
  }
}

// ---------------- GEMM: t[N][384] = A[N][K] @ Wt^T  (Wt [384][K] bf16) ----------------
__device__ __forceinline__ short8 cvt_f32x8(const float* p) {
  f32x4 a = *reinterpret_cast<const f32x4*>(p);
  f32x4 b = *reinterpret_cast<const f32x4*>(p + 4);
  short8 r;
  r[0] = (short)f2bf(a[0]); r[1] = (short)f2bf(a[1]);
  r[2] = (short)f2bf(a[2]); r[3] = (short)f2bf(a[3]);
  r[4] = (short)f2bf(b[0]); r[5] = (short)f2bf(b[1]);
  r[6] = (short)f2bf(b[2]); r[7] = (short)f2bf(b[3]);
  return r;
}

// block: 512 thr (8 waves), 256 rows x 384 cols. wave: rg=w>>1 (64 rows), ch=w&1 (192 cols).
// K-tile = 32. LDS: A [4 kq][256 row]x16B = 16KB, B [4 kq][384 col]x16B = 24.6KB -> 40.9KB.
// A staged chunk-major so ds_read_b128 (16 consecutive lanes = 16 consecutive rows) is
// conflict-free; stage loads are async/deep (global_load_lds for bf16, reg-convert for f32).
template <typename T>
__global__ __launch_bounds__(512) void gemm_kernel(const T* __restrict__ A,
                                                   const unsigned short* __restrict__ Wt,
                                                   unsigned short* __restrict__ out,
                                                   int nrows, int K) {
  __shared__ char lds_raw[40960];  // [0,16384): A ; [16384,40960): B

  int tid = threadIdx.x;
  int lane = tid & 63;
  int w = tid >> 6;
  int rg = w >> 1, ch = w & 1;
  int row0blk = blockIdx.x * 256;
  int row0 = row0blk + rg * 64;
  int l15 = lane & 15, lq = lane >> 4;

  f32x4 acc[12][4];
#pragma unroll
  for (int cf = 0; cf < 12; cf++)
#pragma unroll
    for (int rf = 0; rf < 4; rf++) acc[cf][rf] = (f32x4)(0.0f);

  int tiles = K / 32;
  for (int tile = 0; tile < tiles; ++tile) {
    __syncthreads();
    // ---- stage B: 1536 slots of 16B, slot = q*384 + c ----
#pragma unroll
    for (int it = 0; it < 3; ++it) {
      int slot = it * 512 + tid;
      int q = slot / 384, c = slot - q * 384;
      const unsigned short* g = Wt + (size_t)c * K + tile * 32 + q * 8;
      __builtin_amdgcn_global_load_lds(GLB_CAST(g), LDS_CAST(lds_raw + 16384 + slot * 16), 16, 0, 0);
    }
    // ---- stage A: 1024 slots of 16B, slot = c*256 + row ----
#pragma unroll
    for (int it = 0; it < 2; ++it) {
      int slot = it * 512 + tid;
      int c = slot >> 8, row = slot & 255;
      int grow = row0blk + row;
      if (grow > nrows - 1) grow = nrows - 1;
      if constexpr (sizeof(T) == 2) {
        const T* g = A + (size_t)grow * K + tile * 32 + c * 8;
        __builtin_amdgcn_global_load_lds(GLB_CAST(g), LDS_CAST(lds_raw + slot * 16), 16, 0, 0);
      } else {
        const float* g = (const float*)A + (size_t)grow * K + tile * 32 + c * 8;
        *reinterpret_cast<short8*>(lds_raw + slot * 16) = cvt_f32x8(g);
      }
    }
    __syncthreads();

    // ---- compute: 4 A-frags + 12 B-frags -> 48 MFMA ----
    short8 af[4];
#pragma unroll
    for (int rf = 0; rf < 4; rf++)
      af[rf] = *reinterpret_cast<const short8*>(
          lds_raw + lq * 4096 + (rg * 64 + rf * 16 + l15) * 16);
#pragma unroll
    for (int cf = 0; cf < 12; cf++) {
      const short8 bf = *reinterpret_cast<const short8*>(
          lds_raw + 16384 + (lq * 384 + ch * 192 + cf * 16 + l15) * 16);
#pragma unroll
      for (int rf = 0; rf < 4; rf++)
        acc[cf][rf] = __builtin_amdgcn_mfma_f32_16x16x32_bf16(bf, af[rf], acc[cf][rf], 0, 0, 0);
    }
  }

  // epilogue: lane holds rows row0+rf*16+l15, cols ch*192+cf*16+lq*4 .. +4
#pragma unroll
  for (int rf = 0; rf < 4; rf++) {
    int row = row0 + rf * 16 + l15;
    if (row >= nrows) continue;
    unsigned short* orow = out + (size_t)row * 384 + ch * 192 + lq * 4;
#pragma unroll
    for (int cf = 0; cf < 12; cf++) {
      u32x2 pv;
      pv[0] = (unsigned)f2bf(acc[cf][rf][0]) | ((unsigned)f2bf(acc[cf][rf][1]) << 16);
      pv[1] = (unsigned)f2bf(acc[cf][rf][2]) | ((unsigned)f2bf(acc[cf][rf][3]) << 16);
      *reinterpret_cast<u32x2*>(orow + cf * 16) = pv;
    }
  }
}

// ---------------- SpMM + epilogue ----------------
// t: [N][384] bf16, cols 0..191 = h@w ; cols 192..383 = h@lw
// thread = (node, chunk c of 8 cols); edge loop unrolled x2 for gather MLP.
// mode 0: r = agg + hl + bias            -> out16 (+out32 if given)
// mode 1: r = 0.5*(hprev32 + agg + hl + bias) -> out16 + out32
__global__ __launch_bounds__(256) void spmm_kernel(const unsigned short* __restrict__ t,
                                                   const int* __restrict__ rowptr,
                                                   const int2* __restrict__ s_edge,
                                                   const float* __restrict__ bias,
                                                   const float* __restrict__ hprev32,
                                                   unsigned short* __restrict__ out16,
                                                   float* __restrict__ out32,
                                                   int n, int mode) {
  int tid = blockIdx.x * blockDim.x + threadIdx.x;
  int node = tid / 24;
  int c = tid % 24;
  if (node >= n) return;

  float acc[8];
#pragma unroll
  for (int j = 0; j < 8; j++) acc[j] = 0.0f;

  int e0 = rowptr[node], e1 = rowptr[node + 1];
  int e = e0;
  for (; e + 2 <= e1; e += 2) {
    int2 ra = s_edge[e];
    int2 rb = s_edge[e + 1];
    float wa = __int_as_float(ra.y);
    float wb = __int_as_float(rb.y);
    short8 va = *reinterpret_cast<const short8*>(&t[(size_t)ra.x * 384 + c * 8]);
    short8 vb = *reinterpret_cast<const short8*>(&t[(size_t)rb.x * 384 + c * 8]);
#pragma unroll
    for (int j = 0; j < 8; j++) {
      acc[j] += wa * bf2f((unsigned short)va[j]);
      acc[j] += wb * bf2f((unsigned short)vb[j]);
    }
  }
  if (e < e1) {
    int2 ra = s_edge[e];
    float wa = __int_as_float(ra.y);
    short8 va = *reinterpret_cast<const short8*>(&t[(size_t)ra.x * 384 + c * 8]);
#pragma unroll
    for (int j = 0; j < 8; j++) acc[j] += wa * bf2f((unsigned short)va[j]);
  }

  short8 hlv = *reinterpret_cast<const short8*>(&t[(size_t)node * 384 + 192 + c * 8]);
  float r[8];
#pragma unroll
  for (int j = 0; j < 8; j++)
    r[j] = acc[j] + bf2f((unsigned short)hlv[j]) + bias[c * 8 + j];

  if (mode == 1) {
#pragma unroll
    for (int j = 0; j < 8; j++)
      r[j] = 0.5f * (hprev32[(size_t)node * 192 + c * 8 + j] + r[j]);
  }

  unsigned short o16[8];
#pragma unroll
  for (int j = 0; j < 8; j++) o16[j] = f2bf(r[j]);
  *reinterpret_cast<int4v*>(&out16[(size_t)node * 192 + c * 8]) =
      *reinterpret_cast<const int4v*>(o16);

  if (out32) {
    f32x4 lo, hi;
    lo[0] = r[0]; lo[1] = r[1]; lo[2] = r[2]; lo[3] = r[3];
    hi[0] = r[4]; hi[1] = r[5]; hi[2] = r[6]; hi[3] = r[7];
    *reinterpret_cast<f32x4*>(&out32[(size_t)node * 192 + c * 8]) = lo;
    *reinterpret_cast<f32x4*>(&out32[(size_t)node * 192 + c * 8 + 4]) = hi;
  }
}

// ---------------- conv2 (f32) ----------------
__global__ __launch_bounds__(256) void conv2a_kernel(const float* __restrict__ h,
                                                     const float* __restrict__ w2,
                                                     const float* __restrict__ l2,
                                                     const float* __restrict__ b2,
                                                     float* __restrict__ sup2,
                                                     float* __restrict__ hl2, int n) {
  int wid = (blockIdx.x * blockDim.x + threadIdx.x) >> 6;
  int lane = threadIdx.x & 63;
  if (wid >= n) return;
  float sa[3] = {0.f, 0.f, 0.f}, sl[3] = {0.f, 0.f, 0.f};
  for (int k = lane; k < 192; k += 64) {
    float hv = h[(size_t)wid * 192 + k];
#pragma unroll
    for (int j = 0; j < 3; j++) {
      sa[j] += hv * w2[k * 3 + j];
      sl[j] += hv * l2[k * 3 + j];
    }
  }
#pragma unroll
  for (int j = 0; j < 3; j++) {
    for (int off = 32; off > 0; off >>= 1) {
      sa[j] += __shfl_down(sa[j], off);
      sl[j] += __shfl_down(sl[j], off);
    }
  }
  if (lane == 0) {
#pragma unroll
    for (int j = 0; j < 3; j++) {
      sup2[(size_t)wid * 3 + j] = sa[j];
      hl2[(size_t)wid * 3 + j] = sl[j] + b2[j];
    }
  }
}

__global__ __launch_bounds__(256) void conv2b_kernel(const int* __restrict__ rowptr,
                                                     const int2* __restrict__ s_edge,
                                                     const float* __restrict__ sup2,
                                                     const float* __restrict__ hl2,
                                                     float* __restrict__ out, int n) {
  int node = blockIdx.x * blockDim.x + threadIdx.x;
  if (node >= n) return;
  float acc[3] = {0.f, 0.f, 0.f};
  int e0 = rowptr[node], e1 = rowptr[node + 1];
  for (int e = e0; e < e1; e++) {
    int2 rec = s_edge[e];
    float wgt = __int_as_float(rec.y);
#pragma unroll
    for (int j = 0; j < 3; j++) acc[j] += wgt * sup2[(size_t)rec.x * 3 + j];
  }
#pragma unroll
  for (int j = 0; j < 3; j++)
    out[(size_t)node * 3 + j] = acc[j] + hl2[(size_t)node * 3 + j];
}

extern "C" void kernel_launch(void* const* d_in, const int* in_sizes, int n_in,
                              void* d_out, int out_size, void* d_ws, size_t ws_size,
                              hipStream_t stream) {
  const float* x  = (const float*)d_in[0];
  const int* src  = (const int*)d_in[1];
  const int* dst  = (const int*)d_in[2];
  const float* ew = (const float*)d_in[3];
  const float* w1 = (const float*)d_in[4];
  const float* l1 = (const float*)d_in[5];
  const float* b1 = (const float*)d_in[6];
  const float* wb = (const float*)d_in[7];
  const float* lb = (const float*)d_in[8];
  const float* bb = (const float*)d_in[9];
  const float* w2 = (const float*)d_in[10];
  const float* l2 = (const float*)d_in[11];
  const float* b2 = (const float*)d_in[12];
  float* out = (float*)d_out;

  const int N = in_sizes[0] / 960;   // 100000
  const int E = in_sizes[1];         // 1600000

  float* h32 = out + (size_t)N * 3;  // x_cat region doubles as the f32 master h

  char* p = (char*)d_ws;
  auto alloc = [&](size_t bytes) {
    char* q = p;
    p += (bytes + 255) & ~(size_t)255;
    return q;
  };
  unsigned short* Wt1 = (unsigned short*)alloc((size_t)384 * 960 * 2);
  unsigned short* Wtb = (unsigned short*)alloc((size_t)12 * 384 * 192 * 2);
  unsigned short* t   = (unsigned short*)alloc((size_t)N * 384 * 2);
  unsigned short* h16 = (unsigned short*)alloc((size_t)N * 192 * 2);
  unsigned short* a16 = (unsigned short*)alloc((size_t)N * 192 * 2);
  int* rowptr = (int*)alloc((size_t)(N + 1) * 4);
  int* cur    = (int*)alloc((size_t)N * 4);
  int* cnt    = (int*)alloc((size_t)(N + 1) * 4);
  int2* s_edge = (int2*)alloc((size_t)E * 8);
  float* sup2 = (float*)alloc((size_t)N * 3 * 4);
  float* hl2  = (float*)alloc((size_t)N * 3 * 4);
  if ((size_t)(p - (char*)d_ws) > ws_size) return;  // signature: absmax stays 0.157

  hipMemsetAsync(cnt, 0, (size_t)(N + 1) * 4, stream);
  count_kernel<<<(E + 255) / 256, 256, 0, stream>>>(dst, cnt, E);
  scan_kernel<<<1, 1024, 0, stream>>>(cnt, rowptr, cur, N + 1, N);
  fill_kernel<<<(E + 255) / 256, 256, 0, stream>>>(src, dst, ew, cur, s_edge, E);
  {
    int total = 384 * 960 + 12 * 384 * 192;
    prep_w_kernel<<<(total + 255) / 256, 256, 0, stream>>>(w1, l1, wb, lb, Wt1, Wtb);
  }

  int gBlocks = (N + 255) / 256;
  int sBlocks = (N * 24 + 255) / 256;

  // conv1: t = [x@w1 | x@l1]; h = agg + hl + b1  (f32 master + bf16 mirror)
  gemm_kernel<float><<<gBlocks, 512, 0, stream>>>(x, Wt1, t, N, 960);
  spmm_kernel<<<sBlocks, 256, 0, stream>>>(t, rowptr, s_edge, b1,
                                           (const float*)nullptr, h16, h32, N, 0);

  // res blocks
  for (int i = 0; i < 12; i += 2) {
    gemm_kernel<unsigned short><<<gBlocks, 512, 0, stream>>>(
        h16, Wtb + (size_t)i * 384 * 192, t, N, 192);
    spmm_kernel<<<sBlocks, 256, 0, stream>>>(t, rowptr, s_edge, bb + (size_t)i * 192,
                                             (const float*)nullptr, a16, (float*)nullptr, N, 0);
    gemm_kernel<unsigned short><<<gBlocks, 512, 0, stream>>>(
        a16, Wtb + (size_t)(i + 1) * 384 * 192, t, N, 192);
    spmm_kernel<<<sBlocks, 256, 0, stream>>>(t, rowptr, s_edge, bb + (size_t)(i + 1) * 192,
                                             h32, h16, h32, N, 1);
  }

  // conv2 (f32): x_out = agg(h@w2) + h@l2 + b2
  conv2a_kernel<<<(N + 3) / 4, 256, 0, stream>>>(h32, w2, l2, b2, sup2, hl2, N);
  conv2b_kernel<<<(N + 255) / 256, 256, 0, stream>>>(rowptr, s_edge, sup2, hl2, out, N);
  // x_cat == h32 already lives in the output buffer
}

// Round 5
// 2569.452 us; speedup vs baseline: 1.6486x; 1.1332x over previous
//
#include <hip/hip_runtime.h>

typedef __attribute__((ext_vector_type(8))) short short8;
typedef __attribute__((ext_vector_type(4))) float f32x4;
typedef __attribute__((ext_vector_type(4))) int int4v;
typedef __attribute__((ext_vector_type(2))) unsigned int u32x2;

__device__ __forceinline__ float bf2f(unsigned short u) {
  return __uint_as_float(((unsigned)u) << 16);
}
__device__ __forceinline__ unsigned short f2bf(float f) {
  unsigned u = __float_as_uint(f);
  return (unsigned short)((u + 0x7FFFu + ((u >> 16) & 1u)) >> 16);
}

#define GLB_CAST(p) ((const __attribute__((address_space(1))) void*)(p))
#define LDS_CAST(p) ((__attribute__((address_space(3))) void*)(p))

// ---------------- CSR build ----------------
__global__ void count_kernel(const int* __restrict__ dst, int* __restrict__ cnt, int E) {
  int e = blockIdx.x * blockDim.x + threadIdx.x;
  if (e < E) atomicAdd(&cnt[dst[e] + 1], 1);
}

// pass 1: per-block (1024 elems) sums. 256 thr, 4 elems each.
__global__ __launch_bounds__(256) void scan_bsum_kernel(const int* __restrict__ cnt,
                                                        int* __restrict__ bsum, int n) {
  __shared__ int buf[256];
  int tid = threadIdx.x;
  int j0 = blockIdx.x * 1024 + tid * 4;
  int s = 0;
#pragma unroll
  for (int k = 0; k < 4; k++) {
    int j = j0 + k;
    if (j < n) s += cnt[j];
  }
  buf[tid] = s;
  __syncthreads();
  for (int off = 128; off > 0; off >>= 1) {
    if (tid < off) buf[tid] += buf[tid + off];
    __syncthreads();
  }
  if (tid == 0) bsum[blockIdx.x] = buf[0];
}

// pass 2: single small block: exclusive offsets of block sums (nb <= 256*C)
__global__ __launch_bounds__(256) void scan_small_kernel(const int* __restrict__ bsum,
                                                         int* __restrict__ boff, int nb) {
  __shared__ int buf[2][256];
  int tid = threadIdx.x;
  int C = (nb + 255) >> 8;
  int start = tid * C;
  int end = start + C; if (end > nb) end = nb;
  int s = 0;
  for (int j = start; j < end; j++) s += bsum[j];
  buf[0][tid] = s;
  __syncthreads();
  int pin = 0;
  for (int off = 1; off < 256; off <<= 1) {
    int v = buf[pin][tid];
    if (tid >= off) v += buf[pin][tid - off];
    buf[pin ^ 1][tid] = v;
    pin ^= 1;
    __syncthreads();
  }
  int run = (tid == 0) ? 0 : buf[pin][tid - 1];
  for (int j = start; j < end; j++) {
    boff[j] = run;
    run += bsum[j];
  }
}

// pass 3: per-block local inclusive scan + block offset -> rowptr, cur
__global__ __launch_bounds__(256) void scan_final_kernel(const int* __restrict__ cnt,
                                                         const int* __restrict__ boff,
                                                         int* __restrict__ rowptr,
                                                         int* __restrict__ cur,
                                                         int n, int nrows) {
  __shared__ int buf[2][256];
  int tid = threadIdx.x;
  int j0 = blockIdx.x * 1024 + tid * 4;
  int v[4];
  int s = 0;
#pragma unroll
  for (int k = 0; k < 4; k++) {
    int j = j0 + k;
    v[k] = (j < n) ? cnt[j] : 0;
    s += v[k];
  }
  buf[0][tid] = s;
  __syncthreads();
  int pin = 0;
  for (int off = 1; off < 256; off <<= 1) {
    int t = buf[pin][tid];
    if (tid >= off) t += buf[pin][tid - off];
    buf[pin ^ 1][tid] = t;
    pin ^= 1;
    __syncthreads();
  }
  int run = boff[blockIdx.x] + ((tid == 0) ? 0 : buf[pin][tid - 1]);
#pragma unroll
  for (int k = 0; k < 4; k++) {
    int j = j0 + k;
    if (j < n) {
      run += v[k];
      rowptr[j] = run;           // inclusive scan of cnt == row start of node j
      if (j < nrows) cur[j] = run;
    }
  }
}

__global__ void fill_kernel(const int* __restrict__ src, const int* __restrict__ dst,
                            const float* __restrict__ ew,
                            int* __restrict__ cur, int2* __restrict__ s_edge, int E) {
  int e = blockIdx.x * blockDim.x + threadIdx.x;
  if (e >= E) return;
  int r = dst[e];
  int pos = atomicAdd(&cur[r], 1);
  s_edge[pos] = make_int2(src[e], __float_as_int(ew[e]));
}

// ---------------- weight prep: f32 -> bf16, transpose to [col][k] ----------------
__global__ void prep_w_kernel(const float* __restrict__ w1,
                              const float* __restrict__ l1,
                              const float* __restrict__ wb,
                              const float* __restrict__ lb,
                              unsigned short* __restrict__ Wt1,
                              unsigned short* __restrict__ Wtb) {
  int tid = blockIdx.x * blockDim.x + threadIdx.x;
  const int n1 = 384 * 960;
  const int nb = 12 * 384 * 192;
  if (tid < n1) {
    int c = tid / 960, k = tid % 960;
    Wt1[tid] = f2bf((c < 192) ? w1[k * 192 + c] : l1[k * 192 + (c - 192)]);
  } else if (tid < n1 + nb) {
    int u = tid - n1;
    int i = u / (384 * 192);
    int r = u % (384 * 192);
    int c = r / 192, k = r % 192;
    Wtb[u] = f2bf((c < 192) ? wb[(i * 192 + k) * 192 + c]
                            : lb[(i * 192 + k) * 192 + (c - 192)]);
  }
}

// ---------------- GEMM: t[N][384] = A[N][K] @ Wt^T  (Wt [384][K] bf16) ----------------
__device__ __forceinline__ short8 cvt_f32x8(const float* p) {
  f32x4 a = *reinterpret_cast<const f32x4*>(p);
  f32x4 b = *reinterpret_cast<const f32x4*>(p + 4);
  short8 r;
  r[0] = (short)f2bf(a[0]); r[1] = (short)f2bf(a[1]);
  r[2] = (short)f2bf(a[2]); r[3] = (short)f2bf(a[3]);
  r[4] = (short)f2bf(b[0]); r[5] = (short)f2bf(b[1]);
  r[6] = (short)f2bf(b[2]); r[7] = (short)f2bf(b[3]);
  return r;
}

// block: 512 thr (8 waves), 256 rows x 384 cols. wave: rg=w>>1 (64 rows), ch=w&1 (192 cols).
// K-tile = 32. LDS: A [4 kq][256 row]x16B = 16KB, B [4 kq][384 col]x16B = 24.6KB -> 40.9KB.
template <typename T>
__global__ __launch_bounds__(512) void gemm_kernel(const T* __restrict__ A,
                                                   const unsigned short* __restrict__ Wt,
                                                   unsigned short* __restrict__ out,
                                                   int nrows, int K) {
  __shared__ char lds_raw[40960];  // [0,16384): A ; [16384,40960): B

  int tid = threadIdx.x;
  int lane = tid & 63;
  int w = tid >> 6;
  int rg = w >> 1, ch = w & 1;
  int row0blk = blockIdx.x * 256;
  int row0 = row0blk + rg * 64;
  int l15 = lane & 15, lq = lane >> 4;

  f32x4 acc[12][4];
#pragma unroll
  for (int cf = 0; cf < 12; cf++)
#pragma unroll
    for (int rf = 0; rf < 4; rf++) acc[cf][rf] = (f32x4)(0.0f);

  int tiles = K / 32;
  for (int tile = 0; tile < tiles; ++tile) {
    __syncthreads();
    // ---- stage B: 1536 slots of 16B, slot = q*384 + c ----
#pragma unroll
    for (int it = 0; it < 3; ++it) {
      int slot = it * 512 + tid;
      int q = slot / 384, c = slot - q * 384;
      const unsigned short* g = Wt + (size_t)c * K + tile * 32 + q * 8;
      __builtin_amdgcn_global_load_lds(GLB_CAST(g), LDS_CAST(lds_raw + 16384 + slot * 16), 16, 0, 0);
    }
    // ---- stage A: 1024 slots of 16B, slot = c*256 + row ----
#pragma unroll
    for (int it = 0; it < 2; ++it) {
      int slot = it * 512 + tid;
      int c = slot >> 8, row = slot & 255;
      int grow = row0blk + row;
      if (grow > nrows - 1) grow = nrows - 1;
      if constexpr (sizeof(T) == 2) {
        const T* g = A + (size_t)grow * K + tile * 32 + c * 8;
        __builtin_amdgcn_global_load_lds(GLB_CAST(g), LDS_CAST(lds_raw + slot * 16), 16, 0, 0);
      } else {
        const float* g = (const float*)A + (size_t)grow * K + tile * 32 + c * 8;
        *reinterpret_cast<short8*>(lds_raw + slot * 16) = cvt_f32x8(g);
      }
    }
    __syncthreads();

    // ---- compute: 4 A-frags + 12 B-frags -> 48 MFMA ----
    short8 af[4];
#pragma unroll
    for (int rf = 0; rf < 4; rf++)
      af[rf] = *reinterpret_cast<const short8*>(
          lds_raw + lq * 4096 + (rg * 64 + rf * 16 + l15) * 16);
#pragma unroll
    for (int cf = 0; cf < 12; cf++) {
      const short8 bf = *reinterpret_cast<const short8*>(
          lds_raw + 16384 + (lq * 384 + ch * 192 + cf * 16 + l15) * 16);
#pragma unroll
      for (int rf = 0; rf < 4; rf++)
        acc[cf][rf] = __builtin_amdgcn_mfma_f32_16x16x32_bf16(bf, af[rf], acc[cf][rf], 0, 0, 0);
    }
  }

  // epilogue: lane holds rows row0+rf*16+l15, cols ch*192+cf*16+lq*4 .. +4
#pragma unroll
  for (int rf = 0; rf < 4; rf++) {
    int row = row0 + rf * 16 + l15;
    if (row >= nrows) continue;
    unsigned short* orow = out + (size_t)row * 384 + ch * 192 + lq * 4;
#pragma unroll
    for (int cf = 0; cf < 12; cf++) {
      u32x2 pv;
      pv[0] = (unsigned)f2bf(acc[cf][rf][0]) | ((unsigned)f2bf(acc[cf][rf][1]) << 16);
      pv[1] = (unsigned)f2bf(acc[cf][rf][2]) | ((unsigned)f2bf(acc[cf][rf][3]) << 16);
      *reinterpret_cast<u32x2*>(orow + cf * 16) = pv;
    }
  }
}

// ---------------- SpMM + epilogue ----------------
// t: [N][384] bf16, cols 0..191 = h@w ; cols 192..383 = h@lw
// thread = (node, chunk c of 8 cols); edge loop unrolled x4 for gather MLP.
__global__ __launch_bounds__(256) void spmm_kernel(const unsigned short* __restrict__ t,
                                                   const int* __restrict__ rowptr,
                                                   const int2* __restrict__ s_edge,
                                                   const float* __restrict__ bias,
                                                   const float* __restrict__ hprev32,
                                                   unsigned short* __restrict__ out16,
                                                   float* __restrict__ out32,
                                                   int n, int mode) {
  int tid = blockIdx.x * blockDim.x + threadIdx.x;
  int node = tid / 24;
  int c = tid % 24;
  if (node >= n) return;

  float acc[8];
#pragma unroll
  for (int j = 0; j < 8; j++) acc[j] = 0.0f;

  int e0 = rowptr[node], e1 = rowptr[node + 1];
  int e = e0;
  for (; e + 4 <= e1; e += 4) {
    int2 ra = s_edge[e];
    int2 rb = s_edge[e + 1];
    int2 rc = s_edge[e + 2];
    int2 rd = s_edge[e + 3];
    float wa = __int_as_float(ra.y), wb = __int_as_float(rb.y);
    float wc = __int_as_float(rc.y), wd = __int_as_float(rd.y);
    short8 va = *reinterpret_cast<const short8*>(&t[(size_t)ra.x * 384 + c * 8]);
    short8 vb = *reinterpret_cast<const short8*>(&t[(size_t)rb.x * 384 + c * 8]);
    short8 vc = *reinterpret_cast<const short8*>(&t[(size_t)rc.x * 384 + c * 8]);
    short8 vd = *reinterpret_cast<const short8*>(&t[(size_t)rd.x * 384 + c * 8]);
#pragma unroll
    for (int j = 0; j < 8; j++) {
      acc[j] += wa * bf2f((unsigned short)va[j]) + wb * bf2f((unsigned short)vb[j]) +
                wc * bf2f((unsigned short)vc[j]) + wd * bf2f((unsigned short)vd[j]);
    }
  }
  for (; e < e1; e++) {
    int2 ra = s_edge[e];
    float wa = __int_as_float(ra.y);
    short8 va = *reinterpret_cast<const short8*>(&t[(size_t)ra.x * 384 + c * 8]);
#pragma unroll
    for (int j = 0; j < 8; j++) acc[j] += wa * bf2f((unsigned short)va[j]);
  }

  short8 hlv = *reinterpret_cast<const short8*>(&t[(size_t)node * 384 + 192 + c * 8]);
  float r[8];
#pragma unroll
  for (int j = 0; j < 8; j++)
    r[j] = acc[j] + bf2f((unsigned short)hlv[j]) + bias[c * 8 + j];

  if (mode == 1) {
#pragma unroll
    for (int j = 0; j < 8; j++)
      r[j] = 0.5f * (hprev32[(size_t)node * 192 + c * 8 + j] + r[j]);
  }

  unsigned short o16[8];
#pragma unroll
  for (int j = 0; j < 8; j++) o16[j] = f2bf(r[j]);
  *reinterpret_cast<int4v*>(&out16[(size_t)node * 192 + c * 8]) =
      *reinterpret_cast<const int4v*>(o16);

  if (out32) {
    f32x4 lo, hi;
    lo[0] = r[0]; lo[1] = r[1]; lo[2] = r[2]; lo[3] = r[3];
    hi[0] = r[4]; hi[1] = r[5]; hi[2] = r[6]; hi[3] = r[7];
    *reinterpret_cast<f32x4*>(&out32[(size_t)node * 192 + c * 8]) = lo;
    *reinterpret_cast<f32x4*>(&out32[(size_t)node * 192 + c * 8 + 4]) = hi;
  }
}

// ---------------- conv2 (f32) ----------------
__global__ __launch_bounds__(256) void conv2a_kernel(const float* __restrict__ h,
                                                     const float* __restrict__ w2,
                                                     const float* __restrict__ l2,
                                                     const float* __restrict__ b2,
                                                     float* __restrict__ sup2,
                                                     float* __restrict__ hl2, int n) {
  int wid = (blockIdx.x * blockDim.x + threadIdx.x) >> 6;
  int lane = threadIdx.x & 63;
  if (wid >= n) return;
  float sa[3] = {0.f, 0.f, 0.f}, sl[3] = {0.f, 0.f, 0.f};
  for (int k = lane; k < 192; k += 64) {
    float hv = h[(size_t)wid * 192 + k];
#pragma unroll
    for (int j = 0; j < 3; j++) {
      sa[j] += hv * w2[k * 3 + j];
      sl[j] += hv * l2[k * 3 + j];
    }
  }
#pragma unroll
  for (int j = 0; j < 3; j++) {
    for (int off = 32; off > 0; off >>= 1) {
      sa[j] += __shfl_down(sa[j], off);
      sl[j] += __shfl_down(sl[j], off);
    }
  }
  if (lane == 0) {
#pragma unroll
    for (int j = 0; j < 3; j++) {
      sup2[(size_t)wid * 3 + j] = sa[j];
      hl2[(size_t)wid * 3 + j] = sl[j] + b2[j];
    }
  }
}

__global__ __launch_bounds__(256) void conv2b_kernel(const int* __restrict__ rowptr,
                                                     const int2* __restrict__ s_edge,
                                                     const float* __restrict__ sup2,
                                                     const float* __restrict__ hl2,
                                                     float* __restrict__ out, int n) {
  int node = blockIdx.x * blockDim.x + threadIdx.x;
  if (node >= n) return;
  float acc[3] = {0.f, 0.f, 0.f};
  int e0 = rowptr[node], e1 = rowptr[node + 1];
  for (int e = e0; e < e1; e++) {
    int2 rec = s_edge[e];
    float wgt = __int_as_float(rec.y);
#pragma unroll
    for (int j = 0; j < 3; j++) acc[j] += wgt * sup2[(size_t)rec.x * 3 + j];
  }
#pragma unroll
  for (int j = 0; j < 3; j++)
    out[(size_t)node * 3 + j] = acc[j] + hl2[(size_t)node * 3 + j];
}

extern "C" void kernel_launch(void* const* d_in, const int* in_sizes, int n_in,
                              void* d_out, int out_size, void* d_ws, size_t ws_size,
                              hipStream_t stream) {
  const float* x  = (const float*)d_in[0];
  const int* src  = (const int*)d_in[1];
  const int* dst  = (const int*)d_in[2];
  const float* ew = (const float*)d_in[3];
  const float* w1 = (const float*)d_in[4];
  const float* l1 = (const float*)d_in[5];
  const float* b1 = (const float*)d_in[6];
  const float* wb = (const float*)d_in[7];
  const float* lb = (const float*)d_in[8];
  const float* bb = (const float*)d_in[9];
  const float* w2 = (const float*)d_in[10];
  const float* l2 = (const float*)d_in[11];
  const float* b2 = (const float*)d_in[12];
  float* out = (float*)d_out;

  const int N = in_sizes[0] / 960;   // 100000
  const int E = in_sizes[1];         // 1600000

  float* h32 = out + (size_t)N * 3;  // x_cat region doubles as the f32 master h

  char* p = (char*)d_ws;
  auto alloc = [&](size_t bytes) {
    char* q = p;
    p += (bytes + 255) & ~(size_t)255;
    return q;
  };
  unsigned short* Wt1 = (unsigned short*)alloc((size_t)384 * 960 * 2);
  unsigned short* Wtb = (unsigned short*)alloc((size_t)12 * 384 * 192 * 2);
  unsigned short* t   = (unsigned short*)alloc((size_t)N * 384 * 2);
  unsigned short* h16 = (unsigned short*)alloc((size_t)N * 192 * 2);
  unsigned short* a16 = (unsigned short*)alloc((size_t)N * 192 * 2);
  int* rowptr = (int*)alloc((size_t)(N + 1) * 4);
  int* cur    = (int*)alloc((size_t)N * 4);
  int* cnt    = (int*)alloc((size_t)(N + 1) * 4);
  int* bsum   = (int*)alloc((size_t)1024 * 4);
  int* boff   = (int*)alloc((size_t)1024 * 4);
  int2* s_edge = (int2*)alloc((size_t)E * 8);
  float* sup2 = (float*)alloc((size_t)N * 3 * 4);
  float* hl2  = (float*)alloc((size_t)N * 3 * 4);
  if ((size_t)(p - (char*)d_ws) > ws_size) return;  // signature: absmax stays 0.157

  const int nScan = N + 1;
  const int nBlk = (nScan + 1023) / 1024;  // 98 for N=100000

  hipMemsetAsync(cnt, 0, (size_t)(N + 1) * 4, stream);
  count_kernel<<<(E + 255) / 256, 256, 0, stream>>>(dst, cnt, E);
  scan_bsum_kernel<<<nBlk, 256, 0, stream>>>(cnt, bsum, nScan);
  scan_small_kernel<<<1, 256, 0, stream>>>(bsum, boff, nBlk);
  scan_final_kernel<<<nBlk, 256, 0, stream>>>(cnt, boff, rowptr, cur, nScan, N);
  fill_kernel<<<(E + 255) / 256, 256, 0, stream>>>(src, dst, ew, cur, s_edge, E);
  {
    int total = 384 * 960 + 12 * 384 * 192;
    prep_w_kernel<<<(total + 255) / 256, 256, 0, stream>>>(w1, l1, wb, lb, Wt1, Wtb);
  }

  int gBlocks = (N + 255) / 256;
  int sBlocks = (N * 24 + 255) / 256;

  // conv1: t = [x@w1 | x@l1]; h = agg + hl + b1  (f32 master + bf16 mirror)
  gemm_kernel<float><<<gBlocks, 512, 0, stream>>>(x, Wt1, t, N, 960);
  spmm_kernel<<<sBlocks, 256, 0, stream>>>(t, rowptr, s_edge, b1,
                                           (const float*)nullptr, h16, h32, N, 0);

  // res blocks
  for (int i = 0; i < 12; i += 2) {
    gemm_kernel<unsigned short><<<gBlocks, 512, 0, stream>>>(
        h16, Wtb + (size_t)i * 384 * 192, t, N, 192);
    spmm_kernel<<<sBlocks, 256, 0, stream>>>(t, rowptr, s_edge, bb + (size_t)i * 192,
                                             (const float*)nullptr, a16, (float*)nullptr, N, 0);
    gemm_kernel<unsigned short><<<gBlocks, 512, 0, stream>>>(
        a16, Wtb + (size_t)(i + 1) * 384 * 192, t, N, 192);
    spmm_kernel<<<sBlocks, 256, 0, stream>>>(t, rowptr, s_edge, bb + (size_t)(i + 1) * 192,
                                             h32, h16, h32, N, 1);
  }

  // conv2 (f32): x_out = agg(h@w2) + h@l2 + b2
  conv2a_kernel<<<(N + 3) / 4, 256, 0, stream>>>(h32, w2, l2, b2, sup2, hl2, N);
  conv2b_kernel<<<(N + 255) / 256, 256, 0, stream>>>(rowptr, s_edge, sup2, hl2, out, N);
  // x_cat == h32 already lives in the output buffer
}

// Round 6
// 2528.331 us; speedup vs baseline: 1.6754x; 1.0163x over previous
//
#include <hip/hip_runtime.h>

typedef __attribute__((ext_vector_type(8))) short short8;
typedef __attribute__((ext_vector_type(4))) float f32x4;
typedef __attribute__((ext_vector_type(4))) int int4v;
typedef __attribute__((ext_vector_type(2))) unsigned int u32x2;

__device__ __forceinline__ float bf2f(unsigned short u) {
  return __uint_as_float(((unsigned)u) << 16);
}
__device__ __forceinline__ unsigned short f2bf(float f) {
  unsigned u = __float_as_uint(f);
  return (unsigned short)((u + 0x7FFFu + ((u >> 16) & 1u)) >> 16);
}

#define GLB_CAST(p) ((const __attribute__((address_space(1))) void*)(p))
#define LDS_CAST(p) ((__attribute__((address_space(3))) void*)(p))

// ---------------- CSR build ----------------
__global__ void count_kernel(const int* __restrict__ dst, int* __restrict__ cnt, int E) {
  int e = blockIdx.x * blockDim.x + threadIdx.x;
  if (e < E) atomicAdd(&cnt[dst[e] + 1], 1);
}

__global__ __launch_bounds__(256) void scan_bsum_kernel(const int* __restrict__ cnt,
                                                        int* __restrict__ bsum, int n) {
  __shared__ int buf[256];
  int tid = threadIdx.x;
  int j0 = blockIdx.x * 1024 + tid * 4;
  int s = 0;
#pragma unroll
  for (int k = 0; k < 4; k++) {
    int j = j0 + k;
    if (j < n) s += cnt[j];
  }
  buf[tid] = s;
  __syncthreads();
  for (int off = 128; off > 0; off >>= 1) {
    if (tid < off) buf[tid] += buf[tid + off];
    __syncthreads();
  }
  if (tid == 0) bsum[blockIdx.x] = buf[0];
}

__global__ __launch_bounds__(256) void scan_small_kernel(const int* __restrict__ bsum,
                                                         int* __restrict__ boff, int nb) {
  __shared__ int buf[2][256];
  int tid = threadIdx.x;
  int C = (nb + 255) >> 8;
  int start = tid * C;
  int end = start + C; if (end > nb) end = nb;
  int s = 0;
  for (int j = start; j < end; j++) s += bsum[j];
  buf[0][tid] = s;
  __syncthreads();
  int pin = 0;
  for (int off = 1; off < 256; off <<= 1) {
    int v = buf[pin][tid];
    if (tid >= off) v += buf[pin][tid - off];
    buf[pin ^ 1][tid] = v;
    pin ^= 1;
    __syncthreads();
  }
  int run = (tid == 0) ? 0 : buf[pin][tid - 1];
  for (int j = start; j < end; j++) {
    boff[j] = run;
    run += bsum[j];
  }
}

__global__ __launch_bounds__(256) void scan_final_kernel(const int* __restrict__ cnt,
                                                         const int* __restrict__ boff,
                                                         int* __restrict__ rowptr,
                                                         int* __restrict__ cur,
                                                         int n, int nrows) {
  __shared__ int buf[2][256];
  int tid = threadIdx.x;
  int j0 = blockIdx.x * 1024 + tid * 4;
  int v[4];
  int s = 0;
#pragma unroll
  for (int k = 0; k < 4; k++) {
    int j = j0 + k;
    v[k] = (j < n) ? cnt[j] : 0;
    s += v[k];
  }
  buf[0][tid] = s;
  __syncthreads();
  int pin = 0;
  for (int off = 1; off < 256; off <<= 1) {
    int t = buf[pin][tid];
    if (tid >= off) t += buf[pin][tid - off];
    buf[pin ^ 1][tid] = t;
    pin ^= 1;
    __syncthreads();
  }
  int run = boff[blockIdx.x] + ((tid == 0) ? 0 : buf[pin][tid - 1]);
#pragma unroll
  for (int k = 0; k < 4; k++) {
    int j = j0 + k;
    if (j < n) {
      run += v[k];
      rowptr[j] = run;
      if (j < nrows) cur[j] = run;
    }
  }
}

__global__ void fill_kernel(const int* __restrict__ src, const int* __restrict__ dst,
                            const float* __restrict__ ew,
                            int* __restrict__ cur, int2* __restrict__ s_edge, int E) {
  int e = blockIdx.x * blockDim.x + threadIdx.x;
  if (e >= E) return;
  int r = dst[e];
  int pos = atomicAdd(&cur[r], 1);
  s_edge[pos] = make_int2(src[e], __float_as_int(ew[e]));
}

// ---------------- weight prep: f32 -> bf16, transpose to [col][k] ----------------
__global__ void prep_w_kernel(const float* __restrict__ w1,
                              const float* __restrict__ l1,
                              const float* __restrict__ wb,
                              const float* __restrict__ lb,
                              unsigned short* __restrict__ Wt1,
                              unsigned short* __restrict__ Wtb) {
  int tid = blockIdx.x * blockDim.x + threadIdx.x;
  const int n1 = 384 * 960;
  const int nb = 12 * 384 * 192;
  if (tid < n1) {
    int c = tid / 960, k = tid % 960;
    Wt1[tid] = f2bf((c < 192) ? w1[k * 192 + c] : l1[k * 192 + (c - 192)]);
  } else if (tid < n1 + nb) {
    int u = tid - n1;
    int i = u / (384 * 192);
    int r = u % (384 * 192);
    int c = r / 192, k = r % 192;
    Wtb[u] = f2bf((c < 192) ? wb[(i * 192 + k) * 192 + c]
                            : lb[(i * 192 + k) * 192 + (c - 192)]);
  }
}

// ---------------- GEMM common pieces ----------------
__device__ __forceinline__ short8 cvt_f32x8(const float* p) {
  f32x4 a = *reinterpret_cast<const f32x4*>(p);
  f32x4 b = *reinterpret_cast<const f32x4*>(p + 4);
  short8 r;
  r[0] = (short)f2bf(a[0]); r[1] = (short)f2bf(a[1]);
  r[2] = (short)f2bf(a[2]); r[3] = (short)f2bf(a[3]);
  r[4] = (short)f2bf(b[0]); r[5] = (short)f2bf(b[1]);
  r[6] = (short)f2bf(b[2]); r[7] = (short)f2bf(b[3]);
  return r;
}

// f32-A path (conv1): single-buffered, static 40 KB LDS (keeps VGPR<=128 -> 2 blk/CU).
__global__ __launch_bounds__(512) void gemm_f32_kernel(const float* __restrict__ A,
                                                       const unsigned short* __restrict__ Wt,
                                                       unsigned short* __restrict__ out,
                                                       int nrows, int K) {
  __shared__ char lds_raw[40960];  // [0,16384): A ; [16384,40960): B

  int tid = threadIdx.x;
  int lane = tid & 63;
  int w = tid >> 6;
  int rg = w >> 1, ch = w & 1;
  int row0blk = blockIdx.x * 256;
  int row0 = row0blk + rg * 64;
  int l15 = lane & 15, lq = lane >> 4;

  f32x4 acc[12][4];
#pragma unroll
  for (int cf = 0; cf < 12; cf++)
#pragma unroll
    for (int rf = 0; rf < 4; rf++) acc[cf][rf] = (f32x4)(0.0f);

  int tiles = K / 32;
  for (int tile = 0; tile < tiles; ++tile) {
    __syncthreads();
#pragma unroll
    for (int it = 0; it < 3; ++it) {
      int slot = it * 512 + tid;
      int q = slot / 384, c = slot - q * 384;
      const unsigned short* g = Wt + (size_t)c * K + tile * 32 + q * 8;
      __builtin_amdgcn_global_load_lds(GLB_CAST(g), LDS_CAST(lds_raw + 16384 + slot * 16), 16, 0, 0);
    }
#pragma unroll
    for (int it = 0; it < 2; ++it) {
      int slot = it * 512 + tid;
      int c = slot >> 8, row = slot & 255;
      int grow = row0blk + row;
      if (grow > nrows - 1) grow = nrows - 1;
      const float* g = A + (size_t)grow * K + tile * 32 + c * 8;
      *reinterpret_cast<short8*>(lds_raw + slot * 16) = cvt_f32x8(g);
    }
    __syncthreads();

    short8 af[4];
#pragma unroll
    for (int rf = 0; rf < 4; rf++)
      af[rf] = *reinterpret_cast<const short8*>(
          lds_raw + lq * 4096 + (rg * 64 + rf * 16 + l15) * 16);
#pragma unroll
    for (int cf = 0; cf < 12; cf++) {
      const short8 bf = *reinterpret_cast<const short8*>(
          lds_raw + 16384 + (lq * 384 + ch * 192 + cf * 16 + l15) * 16);
#pragma unroll
      for (int rf = 0; rf < 4; rf++)
        acc[cf][rf] = __builtin_amdgcn_mfma_f32_16x16x32_bf16(bf, af[rf], acc[cf][rf], 0, 0, 0);
    }
  }

#pragma unroll
  for (int rf = 0; rf < 4; rf++) {
    int row = row0 + rf * 16 + l15;
    if (row >= nrows) continue;
    unsigned short* orow = out + (size_t)row * 384 + ch * 192 + lq * 4;
#pragma unroll
    for (int cf = 0; cf < 12; cf++) {
      u32x2 pv;
      pv[0] = (unsigned)f2bf(acc[cf][rf][0]) | ((unsigned)f2bf(acc[cf][rf][1]) << 16);
      pv[1] = (unsigned)f2bf(acc[cf][rf][2]) | ((unsigned)f2bf(acc[cf][rf][3]) << 16);
      *reinterpret_cast<u32x2*>(orow + cf * 16) = pv;
    }
  }
}

// bf16-A path (res blocks): 2-phase double-buffered LDS (80 KB dynamic), one barrier/tile.
// stage(t+1) issued before compute(t); barrier drains the async loads after compute covers
// their latency. All staging via global_load_lds width 16 -> no data VGPRs.
__global__ __launch_bounds__(512) void gemm_bf16_db_kernel(const unsigned short* __restrict__ A,
                                                           const unsigned short* __restrict__ Wt,
                                                           unsigned short* __restrict__ out,
                                                           int nrows, int K) {
  extern __shared__ char lds_db[];  // 2 x (A 16384 + B 24576) = 81920

  int tid = threadIdx.x;
  int lane = tid & 63;
  int w = tid >> 6;
  int rg = w >> 1, ch = w & 1;
  int row0blk = blockIdx.x * 256;
  int row0 = row0blk + rg * 64;
  int l15 = lane & 15, lq = lane >> 4;

  f32x4 acc[12][4];
#pragma unroll
  for (int cf = 0; cf < 12; cf++)
#pragma unroll
    for (int rf = 0; rf < 4; rf++) acc[cf][rf] = (f32x4)(0.0f);

  auto stage = [&](int tile, int buf) {
    char* base = lds_db + buf * 40960;
#pragma unroll
    for (int it = 0; it < 3; ++it) {
      int slot = it * 512 + tid;
      int q = slot / 384, c = slot - q * 384;
      const unsigned short* g = Wt + (size_t)c * K + tile * 32 + q * 8;
      __builtin_amdgcn_global_load_lds(GLB_CAST(g), LDS_CAST(base + 16384 + slot * 16), 16, 0, 0);
    }
#pragma unroll
    for (int it = 0; it < 2; ++it) {
      int slot = it * 512 + tid;
      int c = slot >> 8, row = slot & 255;
      int grow = row0blk + row;
      if (grow > nrows - 1) grow = nrows - 1;
      const unsigned short* g = A + (size_t)grow * K + tile * 32 + c * 8;
      __builtin_amdgcn_global_load_lds(GLB_CAST(g), LDS_CAST(base + slot * 16), 16, 0, 0);
    }
  };

  int tiles = K / 32;
  stage(0, 0);
  __syncthreads();
  int cur = 0;
  for (int tile = 0; tile < tiles; ++tile) {
    if (tile + 1 < tiles) stage(tile + 1, cur ^ 1);
    char* base = lds_db + cur * 40960;
    short8 af[4];
#pragma unroll
    for (int rf = 0; rf < 4; rf++)
      af[rf] = *reinterpret_cast<const short8*>(
          base + lq * 4096 + (rg * 64 + rf * 16 + l15) * 16);
#pragma unroll
    for (int cf = 0; cf < 12; cf++) {
      const short8 bf = *reinterpret_cast<const short8*>(
          base + 16384 + (lq * 384 + ch * 192 + cf * 16 + l15) * 16);
#pragma unroll
      for (int rf = 0; rf < 4; rf++)
        acc[cf][rf] = __builtin_amdgcn_mfma_f32_16x16x32_bf16(bf, af[rf], acc[cf][rf], 0, 0, 0);
    }
    __syncthreads();
    cur ^= 1;
  }

#pragma unroll
  for (int rf = 0; rf < 4; rf++) {
    int row = row0 + rf * 16 + l15;
    if (row >= nrows) continue;
    unsigned short* orow = out + (size_t)row * 384 + ch * 192 + lq * 4;
#pragma unroll
    for (int cf = 0; cf < 12; cf++) {
      u32x2 pv;
      pv[0] = (unsigned)f2bf(acc[cf][rf][0]) | ((unsigned)f2bf(acc[cf][rf][1]) << 16);
      pv[1] = (unsigned)f2bf(acc[cf][rf][2]) | ((unsigned)f2bf(acc[cf][rf][3]) << 16);
      *reinterpret_cast<u32x2*>(orow + cf * 16) = pv;
    }
  }
}

// ---------------- SpMM + epilogue ----------------
// thread = (node, chunk c of 8 cols); 8-deep gather pipeline (recs -> gathers -> FMAs).
__global__ __launch_bounds__(256) void spmm_kernel(const unsigned short* __restrict__ t,
                                                   const int* __restrict__ rowptr,
                                                   const int2* __restrict__ s_edge,
                                                   const float* __restrict__ bias,
                                                   const float* __restrict__ hprev32,
                                                   unsigned short* __restrict__ out16,
                                                   float* __restrict__ out32,
                                                   int n, int mode) {
  int tid = blockIdx.x * blockDim.x + threadIdx.x;
  int node = tid / 24;
  int c = tid % 24;
  if (node >= n) return;

  float acc[8];
#pragma unroll
  for (int j = 0; j < 8; j++) acc[j] = 0.0f;

  int e0 = rowptr[node], e1 = rowptr[node + 1];
  int e = e0;
  for (; e + 8 <= e1; e += 8) {
    int2 rec[8];
#pragma unroll
    for (int k = 0; k < 8; k++) rec[k] = s_edge[e + k];
    short8 v[8];
#pragma unroll
    for (int k = 0; k < 8; k++)
      v[k] = *reinterpret_cast<const short8*>(&t[(size_t)rec[k].x * 384 + c * 8]);
#pragma unroll
    for (int k = 0; k < 8; k++) {
      float wgt = __int_as_float(rec[k].y);
#pragma unroll
      for (int j = 0; j < 8; j++) acc[j] += wgt * bf2f((unsigned short)v[k][j]);
    }
  }
  for (; e + 2 <= e1; e += 2) {
    int2 ra = s_edge[e];
    int2 rb = s_edge[e + 1];
    float wa = __int_as_float(ra.y), wb = __int_as_float(rb.y);
    short8 va = *reinterpret_cast<const short8*>(&t[(size_t)ra.x * 384 + c * 8]);
    short8 vb = *reinterpret_cast<const short8*>(&t[(size_t)rb.x * 384 + c * 8]);
#pragma unroll
    for (int j = 0; j < 8; j++)
      acc[j] += wa * bf2f((unsigned short)va[j]) + wb * bf2f((unsigned short)vb[j]);
  }
  if (e < e1) {
    int2 ra = s_edge[e];
    float wa = __int_as_float(ra.y);
    short8 va = *reinterpret_cast<const short8*>(&t[(size_t)ra.x * 384 + c * 8]);
#pragma unroll
    for (int j = 0; j < 8; j++) acc[j] += wa * bf2f((unsigned short)va[j]);
  }

  short8 hlv = *reinterpret_cast<const short8*>(&t[(size_t)node * 384 + 192 + c * 8]);
  float r[8];
#pragma unroll
  for (int j = 0; j < 8; j++)
    r[j] = acc[j] + bf2f((unsigned short)hlv[j]) + bias[c * 8 + j];

  if (mode == 1) {
#pragma unroll
    for (int j = 0; j < 8; j++)
      r[j] = 0.5f * (hprev32[(size_t)node * 192 + c * 8 + j] + r[j]);
  }

  unsigned short o16[8];
#pragma unroll
  for (int j = 0; j < 8; j++) o16[j] = f2bf(r[j]);
  *reinterpret_cast<int4v*>(&out16[(size_t)node * 192 + c * 8]) =
      *reinterpret_cast<const int4v*>(o16);

  if (out32) {
    f32x4 lo, hi;
    lo[0] = r[0]; lo[1] = r[1]; lo[2] = r[2]; lo[3] = r[3];
    hi[0] = r[4]; hi[1] = r[5]; hi[2] = r[6]; hi[3] = r[7];
    *reinterpret_cast<f32x4*>(&out32[(size_t)node * 192 + c * 8]) = lo;
    *reinterpret_cast<f32x4*>(&out32[(size_t)node * 192 + c * 8 + 4]) = hi;
  }
}

// ---------------- conv2 (f32) ----------------
__global__ __launch_bounds__(256) void conv2a_kernel(const float* __restrict__ h,
                                                     const float* __restrict__ w2,
                                                     const float* __restrict__ l2,
                                                     const float* __restrict__ b2,
                                                     float* __restrict__ sup2,
                                                     float* __restrict__ hl2, int n) {
  int wid = (blockIdx.x * blockDim.x + threadIdx.x) >> 6;
  int lane = threadIdx.x & 63;
  if (wid >= n) return;
  float sa[3] = {0.f, 0.f, 0.f}, sl[3] = {0.f, 0.f, 0.f};
  for (int k = lane; k < 192; k += 64) {
    float hv = h[(size_t)wid * 192 + k];
#pragma unroll
    for (int j = 0; j < 3; j++) {
      sa[j] += hv * w2[k * 3 + j];
      sl[j] += hv * l2[k * 3 + j];
    }
  }
#pragma unroll
  for (int j = 0; j < 3; j++) {
    for (int off = 32; off > 0; off >>= 1) {
      sa[j] += __shfl_down(sa[j], off);
      sl[j] += __shfl_down(sl[j], off);
    }
  }
  if (lane == 0) {
#pragma unroll
    for (int j = 0; j < 3; j++) {
      sup2[(size_t)wid * 3 + j] = sa[j];
      hl2[(size_t)wid * 3 + j] = sl[j] + b2[j];
    }
  }
}

__global__ __launch_bounds__(256) void conv2b_kernel(const int* __restrict__ rowptr,
                                                     const int2* __restrict__ s_edge,
                                                     const float* __restrict__ sup2,
                                                     const float* __restrict__ hl2,
                                                     float* __restrict__ out, int n) {
  int node = blockIdx.x * blockDim.x + threadIdx.x;
  if (node >= n) return;
  float acc[3] = {0.f, 0.f, 0.f};
  int e0 = rowptr[node], e1 = rowptr[node + 1];
  for (int e = e0; e < e1; e++) {
    int2 rec = s_edge[e];
    float wgt = __int_as_float(rec.y);
#pragma unroll
    for (int j = 0; j < 3; j++) acc[j] += wgt * sup2[(size_t)rec.x * 3 + j];
  }
#pragma unroll
  for (int j = 0; j < 3; j++)
    out[(size_t)node * 3 + j] = acc[j] + hl2[(size_t)node * 3 + j];
}

extern "C" void kernel_launch(void* const* d_in, const int* in_sizes, int n_in,
                              void* d_out, int out_size, void* d_ws, size_t ws_size,
                              hipStream_t stream) {
  const float* x  = (const float*)d_in[0];
  const int* src  = (const int*)d_in[1];
  const int* dst  = (const int*)d_in[2];
  const float* ew = (const float*)d_in[3];
  const float* w1 = (const float*)d_in[4];
  const float* l1 = (const float*)d_in[5];
  const float* b1 = (const float*)d_in[6];
  const float* wb = (const float*)d_in[7];
  const float* lb = (const float*)d_in[8];
  const float* bb = (const float*)d_in[9];
  const float* w2 = (const float*)d_in[10];
  const float* l2 = (const float*)d_in[11];
  const float* b2 = (const float*)d_in[12];
  float* out = (float*)d_out;

  const int N = in_sizes[0] / 960;   // 100000
  const int E = in_sizes[1];         // 1600000

  float* h32 = out + (size_t)N * 3;  // x_cat region doubles as the f32 master h

  char* p = (char*)d_ws;
  auto alloc = [&](size_t bytes) {
    char* q = p;
    p += (bytes + 255) & ~(size_t)255;
    return q;
  };
  unsigned short* Wt1 = (unsigned short*)alloc((size_t)384 * 960 * 2);
  unsigned short* Wtb = (unsigned short*)alloc((size_t)12 * 384 * 192 * 2);
  unsigned short* t   = (unsigned short*)alloc((size_t)N * 384 * 2);
  unsigned short* h16 = (unsigned short*)alloc((size_t)N * 192 * 2);
  unsigned short* a16 = (unsigned short*)alloc((size_t)N * 192 * 2);
  int* rowptr = (int*)alloc((size_t)(N + 1) * 4);
  int* cur    = (int*)alloc((size_t)N * 4);
  int* cnt    = (int*)alloc((size_t)(N + 1) * 4);
  int* bsum   = (int*)alloc((size_t)1024 * 4);
  int* boff   = (int*)alloc((size_t)1024 * 4);
  int2* s_edge = (int2*)alloc((size_t)E * 8);
  float* sup2 = (float*)alloc((size_t)N * 3 * 4);
  float* hl2  = (float*)alloc((size_t)N * 3 * 4);
  if ((size_t)(p - (char*)d_ws) > ws_size) return;  // signature: absmax stays 0.157

  const int nScan = N + 1;
  const int nBlk = (nScan + 1023) / 1024;

  hipMemsetAsync(cnt, 0, (size_t)(N + 1) * 4, stream);
  count_kernel<<<(E + 255) / 256, 256, 0, stream>>>(dst, cnt, E);
  scan_bsum_kernel<<<nBlk, 256, 0, stream>>>(cnt, bsum, nScan);
  scan_small_kernel<<<1, 256, 0, stream>>>(bsum, boff, nBlk);
  scan_final_kernel<<<nBlk, 256, 0, stream>>>(cnt, boff, rowptr, cur, nScan, N);
  fill_kernel<<<(E + 255) / 256, 256, 0, stream>>>(src, dst, ew, cur, s_edge, E);
  {
    int total = 384 * 960 + 12 * 384 * 192;
    prep_w_kernel<<<(total + 255) / 256, 256, 0, stream>>>(w1, l1, wb, lb, Wt1, Wtb);
  }

  int gBlocks = (N + 255) / 256;
  int sBlocks = (N * 24 + 255) / 256;
  const int DB_LDS = 81920;

  // conv1: t = [x@w1 | x@l1]; h = agg + hl + b1  (f32 master + bf16 mirror)
  gemm_f32_kernel<<<gBlocks, 512, 0, stream>>>(x, Wt1, t, N, 960);
  spmm_kernel<<<sBlocks, 256, 0, stream>>>(t, rowptr, s_edge, b1,
                                           (const float*)nullptr, h16, h32, N, 0);

  // res blocks (double-buffered bf16 GEMM)
  for (int i = 0; i < 12; i += 2) {
    gemm_bf16_db_kernel<<<gBlocks, 512, DB_LDS, stream>>>(
        h16, Wtb + (size_t)i * 384 * 192, t, N, 192);
    spmm_kernel<<<sBlocks, 256, 0, stream>>>(t, rowptr, s_edge, bb + (size_t)i * 192,
                                             (const float*)nullptr, a16, (float*)nullptr, N, 0);
    gemm_bf16_db_kernel<<<gBlocks, 512, DB_LDS, stream>>>(
        a16, Wtb + (size_t)(i + 1) * 384 * 192, t, N, 192);
    spmm_kernel<<<sBlocks, 256, 0, stream>>>(t, rowptr, s_edge, bb + (size_t)(i + 1) * 192,
                                             h32, h16, h32, N, 1);
  }

  // conv2 (f32): x_out = agg(h@w2) + h@l2 + b2
  conv2a_kernel<<<(N + 3) / 4, 256, 0, stream>>>(h32, w2, l2, b2, sup2, hl2, N);
  conv2b_kernel<<<(N + 255) / 256, 256, 0, stream>>>(rowptr, s_edge, sup2, hl2, out, N);
  // x_cat == h32 already lives in the output buffer
}